// Round 3
// baseline (156.616 us; speedup 1.0000x reference)
//
#include <hip/hip_runtime.h>

#define N_PARTS 62
#define M_SAMP  512
#define D_DIM   256
#define MARGIN  0.2f

typedef unsigned short ushort_t;
typedef __attribute__((ext_vector_type(8))) short bf16x8;   // 8 bf16 = 4 VGPRs
typedef __attribute__((ext_vector_type(4))) float f32x4;

__device__ __forceinline__ ushort_t bf16_rne(float f) {
    unsigned u = __float_as_uint(f);
    unsigned r = u + 0x7fffu + ((u >> 16) & 1u);
    return (ushort_t)(r >> 16);
}

// Swizzled LDS offset (in shorts) of 16B slot q (0..3) of row (0..511).
// tile row = 64 B = 4 slots; q ^= (row>>1)&3 makes the 16-lane frag-read
// groups (rows r0..r0+15, fixed q) start at banks {0,16,4,20,8,24,12,28}:
// exact 2-lane/bank coverage for ds_read_b128 (conflict-free).
__device__ __forceinline__ int lds_off(int row, int q) {
    return row * 32 + ((q ^ ((row >> 1) & 3)) << 3);
}

__global__ void zero_out_kernel(float* __restrict__ out) {
    if (threadIdx.x < 2 * N_PARTS) out[threadIdx.x] = 0.0f;
}

// R2 post-mortem: VGPR_Count stayed 128 because LDS (78 KB) permits
// 2 blocks/CU -> LLVM's occupancy heuristic targets 4 waves/EU -> 128-reg
// budget -> acc[4][8] (128 f32) spills to scratch every K-step (90 MB
// WRITE_SIZE). Fix: pin occupancy at 2 waves/EU (amdgpu_waves_per_eu(2,2))
// AND pad LDS past 80 KB so the LDS-derived occupancy agrees. Budget
// becomes 256 regs/wave; demand ~217 -> spill-free.
__global__ __launch_bounds__(512)
__attribute__((amdgpu_waves_per_eu(2, 2)))
void fused_all_kernel(const float* __restrict__ feat, float* __restrict__ out) {
    const int id = blockIdx.x;
    const int n  = id & 63;          // part (XCD affinity: id%8 == n%8)
    const int ct = id >> 6;          // col-slab (128 cols)
    if (n >= N_PARTS) return;
    const int tid  = threadIdx.x;
    const int wave = tid >> 6, lane = tid & 63;

    __shared__ ushort_t tile[2][512 * 32];   // 2 x 32 KB bf16, swizzled
    __shared__ float sqA[M_SAMP + 544];      // +544 pad: LDS 82 KB -> 1 block/CU
    __shared__ float mrg[8][128][3];         // [wave][slab-local col][hp,hn,ds]

    const int r8 = tid >> 3;                 // row within 64-row group
    const int k4 = tid & 7;                  // float4 column quad
    const float* fb = feat + (size_t)n * (M_SAMP * D_DIM) + (size_t)k4 * 4;

    f32x4 acc[4][8] = {};
    float sqp[8] = {0.f, 0.f, 0.f, 0.f, 0.f, 0.f, 0.f, 0.f};

    // ---- prologue: stage chunk 0 into buf 0
    #pragma unroll
    for (int i = 0; i < 8; ++i) {
        const int row = i * 64 + r8;
        const float4 v = *(const float4*)(fb + (size_t)row * D_DIM);
        ushort4 us;
        us.x = bf16_rne(v.x); us.y = bf16_rne(v.y);
        us.z = bf16_rne(v.z); us.w = bf16_rne(v.w);
        const float fx = __uint_as_float((unsigned)us.x << 16);
        const float fy = __uint_as_float((unsigned)us.y << 16);
        const float fz = __uint_as_float((unsigned)us.z << 16);
        const float fw = __uint_as_float((unsigned)us.w << 16);
        sqp[i] += fx * fx + fy * fy + fz * fz + fw * fw;
        *(ushort4*)(&tile[0][lds_off(row, k4 >> 1) + (k4 & 1) * 4]) = us;
    }
    __syncthreads();

    // ---- main loop: prefetch chunk c+1 (global->reg), MFMA chunk c (LDS),
    //      convert+write chunk c+1 into the other buffer.
    #pragma unroll
    for (int c = 0; c < 8; ++c) {
        float4 nx[8];
        if (c < 7) {
            #pragma unroll
            for (int i = 0; i < 8; ++i)
                nx[i] = *(const float4*)(fb + (size_t)(i * 64 + r8) * D_DIM
                                            + (size_t)(c + 1) * 32);
        }
        const ushort_t* tb = tile[c & 1];
        bf16x8 af[4];
        #pragma unroll
        for (int i = 0; i < 4; ++i)
            af[i] = *(const bf16x8*)(tb + lds_off(wave * 64 + i * 16 + (lane & 15),
                                                  lane >> 4));
        // stream B fragments: one live bf at a time (8 regs vs 32)
        #pragma unroll
        for (int ni = 0; ni < 8; ++ni) {
            const bf16x8 bfv = *(const bf16x8*)(tb + lds_off(ct * 128 + ni * 16 + (lane & 15),
                                                             lane >> 4));
            #pragma unroll
            for (int mi = 0; mi < 4; ++mi)
                acc[mi][ni] = __builtin_amdgcn_mfma_f32_16x16x32_bf16(
                    af[mi], bfv, acc[mi][ni], 0, 0, 0);
        }
        if (c < 7) {
            ushort_t* tn = tile[(c + 1) & 1];
            #pragma unroll
            for (int i = 0; i < 8; ++i) {
                const int row = i * 64 + r8;
                ushort4 us;
                us.x = bf16_rne(nx[i].x); us.y = bf16_rne(nx[i].y);
                us.z = bf16_rne(nx[i].z); us.w = bf16_rne(nx[i].w);
                const float fx = __uint_as_float((unsigned)us.x << 16);
                const float fy = __uint_as_float((unsigned)us.y << 16);
                const float fz = __uint_as_float((unsigned)us.z << 16);
                const float fw = __uint_as_float((unsigned)us.w << 16);
                sqp[i] += fx * fx + fy * fy + fz * fz + fw * fw;
                *(ushort4*)(&tn[lds_off(row, k4 >> 1) + (k4 & 1) * 4]) = us;
            }
        }
        __syncthreads();
    }

    // ---- finalize row sum-of-squares: reduce the 8 k4-partials per row
    #pragma unroll
    for (int i = 0; i < 8; ++i) {
        float s = sqp[i];
        s += __shfl_xor(s, 1);
        s += __shfl_xor(s, 2);
        s += __shfl_xor(s, 4);
        if (k4 == 0) sqA[i * 64 + r8] = s;
    }
    __syncthreads();

    // ---- epilogue: identical to verified R12, SQ reads from LDS sqA.
    // C/D layout: col = lane&15, row = (lane>>4)*4 + reg.
    float sqr[4][4];
    #pragma unroll
    for (int mi = 0; mi < 4; ++mi)
        #pragma unroll
        for (int p = 0; p < 4; ++p)
            sqr[mi][p] = sqA[wave * 64 + mi * 16 + (lane >> 4) * 4 + p];

    #pragma unroll
    for (int ni = 0; ni < 8; ++ni) {
        const int C = ct * 128 + ni * 16 + (lane & 15);   // part-local col
        const float sc = sqA[C];
        const int Cg = C >> 3;                             // label = m>>3
        float ds = 0.f, hp = 0.f, hn = 1e30f;
        #pragma unroll
        for (int mi = 0; mi < 4; ++mi) {
            #pragma unroll
            for (int p = 0; p < 4; ++p) {
                const int R = wave * 64 + mi * 16 + (lane >> 4) * 4 + p;
                const float d2 = sqr[mi][p] + sc - 2.f * acc[mi][ni][p];
                const float d  = __builtin_amdgcn_sqrtf(fmaxf(d2, 0.f));
                ds += d;
                if ((R >> 3) == Cg) hp = fmaxf(hp, d);
                else                hn = fminf(hn, d);
            }
        }
        #pragma unroll
        for (int off = 16; off < 64; off <<= 1) {
            ds += __shfl_xor(ds, off);
            hp = fmaxf(hp, __shfl_xor(hp, off));
            hn = fminf(hn, __shfl_xor(hn, off));
        }
        if (lane < 16) {
            mrg[wave][ni * 16 + lane][0] = hp;
            mrg[wave][ni * 16 + lane][1] = hn;
            mrg[wave][ni * 16 + lane][2] = ds;
        }
    }
    __syncthreads();
    if (tid < 128) {   // col tid of the slab: merge 8 row-strips
        float hp = 0.f, hn = 1e30f, bd = 0.f;
        #pragma unroll
        for (int w = 0; w < 8; ++w) {
            hp = fmaxf(hp, mrg[w][tid][0]);
            hn = fminf(hn, mrg[w][tid][1]);
            bd += mrg[w][tid][2];
        }
        const float bl = fmaxf(MARGIN + hp - hn, 0.f);
        mrg[0][tid][0] = bl;
        mrg[0][tid][1] = bd;
    }
    __syncthreads();
    if (tid < 64) {
        float bl = mrg[0][tid][0] + mrg[0][tid + 64][0];
        float bd = mrg[0][tid][1] + mrg[0][tid + 64][1];
        #pragma unroll
        for (int off = 32; off > 0; off >>= 1) {
            bl += __shfl_xor(bl, off);
            bd += __shfl_xor(bd, off);
        }
        if (lane == 0) {
            atomicAdd(&out[n],           bl * (1.0f / 512.0f));
            atomicAdd(&out[N_PARTS + n], bd * (1.0f / (512.0f * 512.0f)));
        }
    }
}

extern "C" void kernel_launch(void* const* d_in, const int* in_sizes, int n_in,
                              void* d_out, int out_size, void* d_ws, size_t ws_size,
                              hipStream_t stream) {
    const float* feat = (const float*)d_in[0];    // [62, 512, 256] fp32
    float* out = (float*)d_out;                   // [124]
    (void)d_ws; (void)ws_size;                    // no workspace needed

    zero_out_kernel<<<dim3(1), 128, 0, stream>>>(out);
    fused_all_kernel<<<dim3(4 * 64), 512, 0, stream>>>(feat, out);
}

// Round 4
// 92.652 us; speedup vs baseline: 1.6904x; 1.6904x over previous
//
#include <hip/hip_runtime.h>

#define N_PARTS 62
#define M_SAMP  512
#define D_DIM   256
#define MARGIN  0.2f
#define ROWS    (N_PARTS * M_SAMP)   // 31744
#define PART_ELEMS (M_SAMP * D_DIM)  // 131072 bf16 per part

typedef unsigned short ushort_t;
typedef __attribute__((ext_vector_type(8))) short bf16x8;   // 8 bf16 = 4 VGPRs
typedef __attribute__((ext_vector_type(4))) float f32x4;

__device__ __forceinline__ ushort_t bf16_rne(float f) {
    unsigned u = __float_as_uint(f);
    unsigned r = u + 0x7fffu + ((u >> 16) & 1u);
    return (ushort_t)(r >> 16);
}

// K1 (verified baseline): fp32 -> bf16 (RNE), per-row sum-of-squares of the
// ROUNDED values, zero-init d_out. FRAGMENT-MAJOR output: per (part, chunk
// c=k>>5, row-group g=row>>4) a contiguous 1 KB frag block; consuming lane l
// reads F[g*16+(l&15)][c*32+(l>>4)*8..+7] at base + l*16 B.
__global__ __launch_bounds__(256) void prep_kernel(const float* __restrict__ feat,
                                                   ushort_t* __restrict__ Fb,
                                                   float* __restrict__ sq,
                                                   float* __restrict__ out) {
    const int id = blockIdx.x;       // id = rb*64 + n
    const int n  = id & 63;          // part
    const int rb = id >> 6;          // row-quad within part (0..127)
    if (id == 0 && threadIdx.x < 2 * N_PARTS) out[threadIdx.x] = 0.0f;
    if (n >= N_PARTS) return;
    const int wv   = threadIdx.x >> 6;            // wave -> one row
    const int lane = threadIdx.x & 63;
    const int rp   = rb * 4 + wv;                 // part-local row
    const int row  = n * M_SAMP + rp;             // global row
    const float4 v = ((const float4*)(feat + (size_t)row * D_DIM))[lane];
    ushort4 us;
    us.x = bf16_rne(v.x); us.y = bf16_rne(v.y);
    us.z = bf16_rne(v.z); us.w = bf16_rne(v.w);
    const float fx = __uint_as_float((unsigned)us.x << 16);
    const float fy = __uint_as_float((unsigned)us.y << 16);
    const float fz = __uint_as_float((unsigned)us.z << 16);
    const float fw = __uint_as_float((unsigned)us.w << 16);
    const int c  = lane >> 3;
    const int q  = (lane >> 1) & 3;
    const int g  = rp >> 4;
    const int fl = (rp & 15) | (q << 4);          // frag lane
    *(ushort4*)(Fb + (size_t)n * PART_ELEMS + ((size_t)(c * 32 + g) * 512)
                + fl * 8 + (lane & 1) * 4) = us;
    float ssum = fx * fx + fy * fy + fz * fz + fw * fw;
    #pragma unroll
    for (int off = 32; off > 0; off >>= 1) ssum += __shfl_xor(ssum, off);
    if (lane == 0) sq[row] = ssum;
}

// K2, spill-free revision. R1-R3 post-mortem: the backend pins this kernel
// shape at a 128-VGPR budget regardless of launch_bounds/waves_per_eu/LDS
// padding; acc[4][8] (128 f32) + operands can never fit -> ~90 MB/dispatch
// scratch spill -> 90 us latency-bound. Fix: 64x64 per-wave tile
// (acc[4][4] = 64 regs), 64-col slabs (grid 8x64, XCD affinity id%8==n%8),
// B fragments streamed one at a time. Main-loop demand ~110 < 128.
// The extra A-panel re-reads (8x vs 4x per part) are L2-resident: ~5 us.
__global__ __launch_bounds__(512)
__attribute__((amdgpu_waves_per_eu(2, 4)))
void gram_kernel(const ushort_t* __restrict__ Fb, const float* __restrict__ sq,
                 float* __restrict__ out) {
    const int id = blockIdx.x;
    const int n  = id & 63;          // part (XCD affinity: id%8 == n%8)
    const int ct = id >> 6;          // col-slab (64 cols, 0..7)
    if (n >= N_PARTS) return;
    const int tid  = threadIdx.x;
    const int wave = tid >> 6, lane = tid & 63;
    const ushort_t* F = Fb + (size_t)n * PART_ELEMS;
    const float* SQ = sq + n * M_SAMP;

    __shared__ float mrg[8][64][3];   // [wave][slab-local col][hp,hn,ds]

    const ushort_t* aptr = F + (size_t)(wave * 4) * 512 + lane * 8;  // rows w*64..
    const ushort_t* bptr = F + (size_t)(ct * 4) * 512 + lane * 8;    // 64 slab cols

    f32x4 acc[4][4] = {};

    #pragma unroll
    for (int c = 0; c < 8; ++c) {
        const size_t off = (size_t)c * (32 * 512);
        bf16x8 af[4];
        #pragma unroll
        for (int i = 0; i < 4; ++i)
            af[i] = *(const bf16x8*)(aptr + off + (size_t)i * 512);
        // stream B fragments: one live at a time (8 regs, not 32)
        #pragma unroll
        for (int ni = 0; ni < 4; ++ni) {
            const bf16x8 bfv = *(const bf16x8*)(bptr + off + (size_t)ni * 512);
            #pragma unroll
            for (int mi = 0; mi < 4; ++mi)
                acc[mi][ni] = __builtin_amdgcn_mfma_f32_16x16x32_bf16(
                    af[mi], bfv, acc[mi][ni], 0, 0, 0);
        }
    }

    // Epilogue (verified R12 structure). C/D layout: col = lane&15,
    // row = (lane>>4)*4 + reg.
    float sqr[4][4];
    #pragma unroll
    for (int mi = 0; mi < 4; ++mi)
        #pragma unroll
        for (int p = 0; p < 4; ++p)
            sqr[mi][p] = SQ[wave * 64 + mi * 16 + (lane >> 4) * 4 + p];

    #pragma unroll
    for (int ni = 0; ni < 4; ++ni) {
        const int C = ct * 64 + ni * 16 + (lane & 15);     // part-local col
        const float sc = SQ[C];
        const int Cg = C >> 3;                             // label = m>>3
        float ds = 0.f, hp = 0.f, hn = 1e30f;
        #pragma unroll
        for (int mi = 0; mi < 4; ++mi) {
            #pragma unroll
            for (int p = 0; p < 4; ++p) {
                const int R = wave * 64 + mi * 16 + (lane >> 4) * 4 + p;
                const float d2 = sqr[mi][p] + sc - 2.f * acc[mi][ni][p];
                const float d  = __builtin_amdgcn_sqrtf(fmaxf(d2, 0.f));
                ds += d;
                if ((R >> 3) == Cg) hp = fmaxf(hp, d);
                else                hn = fminf(hn, d);
            }
        }
        // combine the 4 quads (same col, disjoint row subsets)
        #pragma unroll
        for (int off = 16; off < 64; off <<= 1) {
            ds += __shfl_xor(ds, off);
            hp = fmaxf(hp, __shfl_xor(hp, off));
            hn = fminf(hn, __shfl_xor(hn, off));
        }
        if (lane < 16) {
            mrg[wave][ni * 16 + lane][0] = hp;
            mrg[wave][ni * 16 + lane][1] = hn;
            mrg[wave][ni * 16 + lane][2] = ds;
        }
    }
    __syncthreads();
    if (tid < 64) {   // col tid of the slab: merge 8 row-strips, then reduce
        float hp = 0.f, hn = 1e30f, bd = 0.f;
        #pragma unroll
        for (int w = 0; w < 8; ++w) {
            hp = fmaxf(hp, mrg[w][tid][0]);
            hn = fminf(hn, mrg[w][tid][1]);
            bd += mrg[w][tid][2];
        }
        float bl = fmaxf(MARGIN + hp - hn, 0.f);
        #pragma unroll
        for (int off = 32; off > 0; off >>= 1) {
            bl += __shfl_xor(bl, off);
            bd += __shfl_xor(bd, off);
        }
        if (tid == 0) {
            atomicAdd(&out[n],           bl * (1.0f / 512.0f));
            atomicAdd(&out[N_PARTS + n], bd * (1.0f / (512.0f * 512.0f)));
        }
    }
}

extern "C" void kernel_launch(void* const* d_in, const int* in_sizes, int n_in,
                              void* d_out, int out_size, void* d_ws, size_t ws_size,
                              hipStream_t stream) {
    const float* feat = (const float*)d_in[0];    // [62, 512, 256] fp32
    float* out = (float*)d_out;                   // [124]

    ushort_t* Fb = (ushort_t*)d_ws;                                   // frag-major bf16
    float* sq    = (float*)((char*)d_ws + (size_t)ROWS * D_DIM * 2);  // row sum-of-squares

    prep_kernel<<<dim3(128 * 64), 256, 0, stream>>>(feat, Fb, sq, out);
    gram_kernel<<<dim3(8 * 64), 512, 0, stream>>>(Fb, sq, out);
}